// Round 1
// baseline (199.724 us; speedup 1.0000x reference)
//
#include <hip/hip_runtime.h>

// ECE: ece = sum_b | sum_conf_b - sum_acc_b | / n
//    = sum_b | sum_{i in b} (conf_i - acc_i) | / n   (one diff-histogram)
// Bin: idx = ceil(c*15)-1, valid iff 0 < c <= 1 (same fp32 ops as reference).

#define NB 15

__global__ void ece_zero_bins(float* __restrict__ gbins) {
    if (threadIdx.x < NB) gbins[threadIdx.x] = 0.0f;
}

__global__ __launch_bounds__(256) void ece_hist(
        const float* __restrict__ conf,
        const float* __restrict__ acc,
        float* __restrict__ gbins,
        int n4, int n) {
    constexpr int REPS = 16;   // sub-histogram replicas (lane & 15)
    constexpr int STR  = 17;   // +1 pad: spreads replicas across banks
    __shared__ float lds[REPS * STR];

    for (int i = threadIdx.x; i < REPS * STR; i += blockDim.x) lds[i] = 0.0f;
    __syncthreads();

    const int rep_base = (threadIdx.x & (REPS - 1)) * STR;
    const float4* __restrict__ c4 = (const float4*)conf;
    const float4* __restrict__ a4 = (const float4*)acc;

    const int stride = gridDim.x * blockDim.x;
    for (int i = blockIdx.x * blockDim.x + threadIdx.x; i < n4; i += stride) {
        float4 c = c4[i];
        float4 a = a4[i];
        float cv[4] = {c.x, c.y, c.z, c.w};
        float av[4] = {a.x, a.y, a.z, a.w};
#pragma unroll
        for (int j = 0; j < 4; ++j) {
            float v = cv[j];
            if (v > 0.0f && v <= 1.0f) {
                int idx = (int)ceilf(v * 15.0f) - 1;
                idx = min(max(idx, 0), NB - 1);
                atomicAdd(&lds[rep_base + idx], v - av[j]);
            }
        }
    }

    // scalar tail (n not divisible by 4) — handled by block 0 only
    if (blockIdx.x == 0) {
        for (int i = n4 * 4 + (int)threadIdx.x; i < n; i += blockDim.x) {
            float v = conf[i];
            if (v > 0.0f && v <= 1.0f) {
                int idx = (int)ceilf(v * 15.0f) - 1;
                idx = min(max(idx, 0), NB - 1);
                atomicAdd(&lds[rep_base + idx], v - acc[i]);
            }
        }
    }
    __syncthreads();

    if (threadIdx.x < NB) {
        float s = 0.0f;
#pragma unroll
        for (int r = 0; r < REPS; ++r) s += lds[r * STR + threadIdx.x];
        atomicAdd(&gbins[threadIdx.x], s);
    }
}

__global__ void ece_final(const float* __restrict__ gbins,
                          float* __restrict__ out, float inv_n) {
    if (threadIdx.x == 0) {
        float s = 0.0f;
#pragma unroll
        for (int b = 0; b < NB; ++b) s += fabsf(gbins[b]);
        out[0] = s * inv_n;
    }
}

extern "C" void kernel_launch(void* const* d_in, const int* in_sizes, int n_in,
                              void* d_out, int out_size, void* d_ws, size_t ws_size,
                              hipStream_t stream) {
    const float* conf = (const float*)d_in[0];
    const float* acc  = (const float*)d_in[1];
    float* gbins = (float*)d_ws;       // 15 floats of scratch
    float* out   = (float*)d_out;

    const int n  = in_sizes[0];
    const int n4 = n / 4;

    ece_zero_bins<<<1, 64, 0, stream>>>(gbins);

    const int block = 256;
    int grid = 2048;                   // 8 blocks/CU, grid-stride over 4M float4s
    int max_grid = (n4 + block - 1) / block;
    if (grid > max_grid) grid = max_grid;
    if (grid < 1) grid = 1;
    ece_hist<<<grid, block, 0, stream>>>(conf, acc, gbins, n4, n);

    ece_final<<<1, 64, 0, stream>>>(gbins, out, 1.0f / (float)n);
}

// Round 2
// 161.004 us; speedup vs baseline: 1.2405x; 1.2405x over previous
//
#include <hip/hip_runtime.h>

// ECE: ece = sum_b | sum_{i in b} (conf_i - acc_i) | / n
// Bin: idx = ceil(c*15)-1, valid iff 0 < c <= 1 (same fp32 ops as reference).
// Atomic-free: per-thread register bins -> wave shuffle reduce -> block LDS
// reduce -> per-block partial slots in d_ws -> tiny final reduction kernel.

#define NB 15

__global__ __launch_bounds__(256) void ece_hist(
        const float* __restrict__ conf,
        const float* __restrict__ acc,
        float* __restrict__ partials,   // layout [NB][nblocks]
        int n4, int n, int nblocks) {
    float bins[NB];
#pragma unroll
    for (int b = 0; b < NB; ++b) bins[b] = 0.0f;

    const float4* __restrict__ c4 = (const float4*)conf;
    const float4* __restrict__ a4 = (const float4*)acc;
    const int stride = gridDim.x * blockDim.x;

    for (int i = blockIdx.x * blockDim.x + threadIdx.x; i < n4; i += stride) {
        float4 c = c4[i];
        float4 a = a4[i];
        float cv[4] = {c.x, c.y, c.z, c.w};
        float av[4] = {a.x, a.y, a.z, a.w};
#pragma unroll
        for (int j = 0; j < 4; ++j) {
            float v = cv[j];
            float d = v - av[j];
            int idx = (int)ceilf(v * 15.0f) - 1;
            bool valid = (v > 0.0f) && (v <= 1.0f);
            idx = valid ? idx : -1;          // invalid matches no bin
#pragma unroll
            for (int b = 0; b < NB; ++b)
                bins[b] += (idx == b) ? d : 0.0f;
        }
    }

    // scalar tail (n not divisible by 4) — block 0 only
    if (blockIdx.x == 0) {
        for (int i = n4 * 4 + (int)threadIdx.x; i < n; i += blockDim.x) {
            float v = conf[i];
            float d = v - acc[i];
            int idx = (int)ceilf(v * 15.0f) - 1;
            bool valid = (v > 0.0f) && (v <= 1.0f);
            idx = valid ? idx : -1;
#pragma unroll
            for (int b = 0; b < NB; ++b)
                bins[b] += (idx == b) ? d : 0.0f;
        }
    }

    // wave reduction (64 lanes)
#pragma unroll
    for (int b = 0; b < NB; ++b) {
        float v = bins[b];
#pragma unroll
        for (int off = 32; off > 0; off >>= 1)
            v += __shfl_down(v, off, 64);
        bins[b] = v;
    }

    __shared__ float wsum[4][NB];       // 256 threads = 4 waves
    const int wave = threadIdx.x >> 6;
    const int lane = threadIdx.x & 63;
    if (lane == 0) {
#pragma unroll
        for (int b = 0; b < NB; ++b) wsum[wave][b] = bins[b];
    }
    __syncthreads();

    if (threadIdx.x < NB) {
        float s = wsum[0][threadIdx.x] + wsum[1][threadIdx.x]
                + wsum[2][threadIdx.x] + wsum[3][threadIdx.x];
        partials[threadIdx.x * nblocks + blockIdx.x] = s;   // no atomics
    }
}

__global__ __launch_bounds__(960) void ece_final(
        const float* __restrict__ partials,  // [NB][nblocks]
        float* __restrict__ out, int nblocks, float inv_n) {
    __shared__ float bsum[NB];
    const int wave = threadIdx.x >> 6;   // 15 waves, one per bin
    const int lane = threadIdx.x & 63;

    float s = 0.0f;
    for (int i = lane; i < nblocks; i += 64)
        s += partials[wave * nblocks + i];   // coalesced per wave
#pragma unroll
    for (int off = 32; off > 0; off >>= 1)
        s += __shfl_down(s, off, 64);
    if (lane == 0) bsum[wave] = s;
    __syncthreads();

    if (threadIdx.x == 0) {
        float t = 0.0f;
#pragma unroll
        for (int b = 0; b < NB; ++b) t += fabsf(bsum[b]);
        out[0] = t * inv_n;
    }
}

extern "C" void kernel_launch(void* const* d_in, const int* in_sizes, int n_in,
                              void* d_out, int out_size, void* d_ws, size_t ws_size,
                              hipStream_t stream) {
    const float* conf = (const float*)d_in[0];
    const float* acc  = (const float*)d_in[1];
    float* partials   = (float*)d_ws;
    float* out        = (float*)d_out;

    const int n  = in_sizes[0];
    const int n4 = n / 4;

    int nblocks = 2048;                          // 8 blocks/CU
    // fit in workspace (needs NB*nblocks floats)
    while ((size_t)NB * nblocks * sizeof(float) > ws_size && nblocks > 1)
        nblocks >>= 1;
    int max_grid = (n4 + 255) / 256;
    if (nblocks > max_grid) nblocks = max_grid;
    if (nblocks < 1) nblocks = 1;

    ece_hist<<<nblocks, 256, 0, stream>>>(conf, acc, partials, n4, n, nblocks);
    ece_final<<<1, 960, 0, stream>>>(partials, out, nblocks, 1.0f / (float)n);
}